// Round 7
// baseline (1523.164 us; speedup 1.0000x reference)
//
#include <hip/hip_runtime.h>

// Problem: S=512, B=256, I=64, H=512, O=25.
// y depends only on batch row 255 -> compute only that row's recurrence.
//
// rnn_pre : xi[t][h] = x[t,255,:].W_ih[h,:] + b_ih[h] + b_hh[h]; re-inits the
//           agent exchange buffers (sign=1 = not-ready) and the step-stamped
//           sc buffers (stamp=0xFFFFFFFF) every launch.
// rnn_seq : 512 sequential steps h = relu(xi_t + W_hh h_prev), 16 worker
//           blocks x 256 threads (32 rows each, W_hh register-resident).
//           Workers are blocks with blockIdx%8==0 of a 128-grid: under the
//           observed round-robin dispatch they land on ONE XCD. This is a
//           HEURISTIC (G16): correctness never depends on it.
//           Exchange, two paths per step:
//             fast: producer u64 {h, step} -> sc0 store (local L2); consumer
//                   <=6 bounded sc0 dwordx4 polls, accept ONLY on exact
//                   step-stamp match (stale-L2-line proof), double-buffered.
//             safe: the PROVEN agent-scope protocol (787->637us kernels):
//                   u32 words, generation in SIGN BIT (relu => h>=0),
//                   buffer by s&1, phase=(s>>1)&1, skew<2 invariant;
//                   unbounded poll with adaptive delay D. Producers ALWAYS
//                   dual-store; consumers fall back per step; sticky-off
//                   disables sc polls after 4 missed steps. No hang mode.
//           Intra-block: in-wave production -- wave w owns 8 rows, lane =
//           (row, 64-wide k-chunk), row sum via 3 shfl_xor; h in padded
//           double-buffered LDS [2][8*68] (conflict-free b128); ONE
//           lgkm-only barrier per step (no part[], no barrier A).
// rnn_post: y[t] = h_t . W2^T + b2 (512x25).
//
// Workspace: xh[512*512] (xi, progressively overwritten by hseq: each block
// writes h only over its OWN already-consumed xi rows; strictly ordered),
// hg[2*512] u32 agent exchange, sc[2*512] u64 step-stamped fast exchange.

#define S_ 512
#define B_ 256
#define I_ 64
#define H_ 512
#define O_ 25
#define G_ 16    // worker blocks
#define R_ 32    // rows per worker
#define NC_ 128  // candidate grid (workers = blockIdx%8==0)
#define PAD_ 68  // padded k-chunk stride (64+4): bank-spreads b128 reads
#define PADI(i) ((((i) >> 6) * PAD_) + ((i) & 63))

typedef unsigned u32x4 __attribute__((ext_vector_type(4)));

// lgkm-only barrier: no vmcnt(0) drain -> exchange stores / xi prefetch stay
// in flight across it. sched_barrier(0) fences compiler motion (rule #18).
static __device__ __forceinline__ void wg_barrier_lds() {
  __builtin_amdgcn_sched_barrier(0);
  asm volatile("s_waitcnt lgkmcnt(0)" ::: "memory");
  __builtin_amdgcn_s_barrier();
  __builtin_amdgcn_sched_barrier(0);
}

__global__ __launch_bounds__(256) void rnn_pre(
    const float* __restrict__ x, const float* __restrict__ W_ih,
    const float* __restrict__ b_ih, const float* __restrict__ b_hh,
    float* __restrict__ xh, unsigned* __restrict__ hg) {
  const int t = blockIdx.x;
  const int tid = threadIdx.x;
  const int o = blockIdx.y * 256 + tid;
  if (t == 0 && blockIdx.y == 0) {
    // re-init every launch: no reliance on workspace poison / prior state.
    hg[tid] = 0x80000000u;
    hg[tid + 256] = 0x80000000u;
    hg[tid + 512] = 0x80000000u;
    hg[tid + 768] = 0x80000000u;
    unsigned long long* sc = (unsigned long long*)(hg + 2 * H_);
    sc[tid] = 0xFFFFFFFF00000000ull;          // stamp=~0 != any step
    sc[tid + 256] = 0xFFFFFFFF00000000ull;
    sc[tid + 512] = 0xFFFFFFFF00000000ull;
    sc[tid + 768] = 0xFFFFFFFF00000000ull;
  }
  __shared__ float xr[I_];
  if (tid < I_) xr[tid] = x[(t * B_ + (B_ - 1)) * I_ + tid];
  __syncthreads();
  float acc = b_ih[o] + b_hh[o];
  const float4* wp = (const float4*)(W_ih + o * I_);
#pragma unroll
  for (int j = 0; j < I_ / 4; ++j) {
    float4 w4 = wp[j];
    acc += w4.x * xr[4 * j] + w4.y * xr[4 * j + 1] + w4.z * xr[4 * j + 2] +
           w4.w * xr[4 * j + 3];
  }
  xh[t * H_ + o] = acc;
}

__global__ __launch_bounds__(256) void rnn_seq(
    const float* __restrict__ W_hh, float* __restrict__ xh,
    unsigned* hg) {
  if (blockIdx.x & 7) return;      // workers: one per round-robin XCD slot
  const int b = blockIdx.x >> 3;   // 0..15
  const int tid = threadIdx.x;
  const int kc = tid & 7;                                 // 64-wide k-chunk
  const int rloc = ((tid >> 6) << 3) | ((tid >> 3) & 7);  // row in block
  const int own_lo = b * R_;
  const bool prod = (tid & 7) == 0;   // 32 producers, 8 per wave
  const int grow = own_lo + rloc;     // producer's global row

  unsigned long long* sc = (unsigned long long*)(hg + 2 * H_);

  __shared__ __align__(16) float hbuf[2][8 * PAD_];  // dbuf by step parity

  // W_hh register-resident: thread holds W_hh[own_lo+rloc][kc*64 .. +64).
  float w[64];
  {
    const float4* wp = (const float4*)(W_hh + (own_lo + rloc) * H_ + kc * 64);
#pragma unroll
    for (int j = 0; j < 16; ++j) {
      float4 v = wp[j];
      w[4 * j] = v.x; w[4 * j + 1] = v.y;
      w[4 * j + 2] = v.z; w[4 * j + 3] = v.w;
    }
  }
  for (int n = tid; n < 2 * 8 * PAD_; n += 256) ((float*)hbuf)[n] = 0.0f;

  float xiv = prod ? xh[grow] : 0.0f;  // xi for step 0

  // poll pair: global words 2*tid, 2*tid+1; own block's pairs are skipped
  // (producers write own rows to LDS directly).
  const bool ownp = (tid >= b * (R_ / 2)) && (tid < (b + 1) * (R_ / 2));
  const unsigned long long sm = 0x8000000080000000ull;
  int D = 0;        // agent-path adaptive pre-poll delay (s_sleep units)
  int miss = 0;     // consecutive steps with no sc hit
  bool scOn = true; // sticky sc-path enable
  wg_barrier_lds();

  for (int s = 0; s < S_; ++s) {
    const int ps = s & 1;
    // ---- in-wave matvec: 64 FMA, 4 chains; rows share via broadcast ----
    float a0 = 0.f, a1 = 0.f, a2 = 0.f, a3 = 0.f;
    const float4* hp = (const float4*)(&hbuf[ps][kc * PAD_]);
#pragma unroll
    for (int j = 0; j < 16; ++j) {
      float4 hv = hp[j];
      a0 = fmaf(w[4 * j + 0], hv.x, a0);
      a1 = fmaf(w[4 * j + 1], hv.y, a1);
      a2 = fmaf(w[4 * j + 2], hv.z, a2);
      a3 = fmaf(w[4 * j + 3], hv.w, a3);
    }
    float acc = (a0 + a1) + (a2 + a3);
    acc += __shfl_xor(acc, 1);   // fold the 8 k-chunks of this row
    acc += __shfl_xor(acc, 2);
    acc += __shfl_xor(acc, 4);

    const unsigned phase = (unsigned)((s >> 1) & 1);
    unsigned* buf = hg + ps * H_;
    unsigned long long* scb = sc + ps * H_;

    if (prod) {
      float h = fmaxf(acc + xiv, 0.0f);
      unsigned hb = __float_as_uint(h);
      // fast copy first: {h, step} u64 via sc0 (lands in local L2).
      unsigned long long sv =
          ((unsigned long long)(unsigned)s << 32) | (unsigned long long)hb;
      unsigned long long* sp = scb + grow;
      asm volatile("global_store_dwordx2 %0, %1, off sc0"
                   :: "v"(sp), "v"(sv) : "memory");
      // safe copy: proven agent-scope sign-tagged word.
      __hip_atomic_store(&buf[grow], hb | (phase << 31),
                         __ATOMIC_RELAXED, __HIP_MEMORY_SCOPE_AGENT);
      hbuf[ps ^ 1][PADI(grow)] = h;     // own row -> next read buffer
      xh[s * H_ + grow] = h;            // hseq (over consumed xi rows)
    }

    if (s == S_ - 1) break;  // no poll needed after last step

    // prefetch next step's xi (in flight under the poll)
    if (prod) xiv = xh[(s + 1) * H_ + grow];

    if (!ownp) {
      bool got = false;
      float2 hv2;
      if (scOn) {
        const u32x4* sp4 = (const u32x4*)scb + tid;  // rows 2tid, 2tid+1
        for (int it = 0; it < 6; ++it) {
          u32x4 v;
          asm volatile(
              "global_load_dwordx4 %0, %1, off sc0\n\ts_waitcnt vmcnt(0)"
              : "=v"(v) : "v"(sp4) : "memory");
          if (v.y == (unsigned)s && v.w == (unsigned)s) {
            hv2.x = __uint_as_float(v.x);
            hv2.y = __uint_as_float(v.z);
            got = true;
            break;
          }
        }
        if (s >= 8) {  // ignore startup skew
          if (got) miss = 0;
          else if (++miss >= 4) scOn = false;  // heuristic failed: go agent
        }
      }
      if (!got) {  // PROVEN agent poll (R5), unbounded, guaranteed
        for (int d = 0; d < D; ++d) __builtin_amdgcn_s_sleep(1);
        const unsigned long long ph64 = phase ? sm : 0ull;
        const unsigned long long* ap = (const unsigned long long*)buf + tid;
        unsigned long long v;
        int n = 0;
        do {
          v = __hip_atomic_load(ap, __ATOMIC_RELAXED,
                                __HIP_MEMORY_SCOPE_AGENT);
          ++n;
        } while (((v ^ ph64) & sm) != 0ull);
        hv2.x = __uint_as_float((unsigned)v & 0x7fffffffu);
        hv2.y = __uint_as_float((unsigned)(v >> 32) & 0x7fffffffu);
        if (n > 1) {
          D += 8 * (n - 1);
          if (D > 48) D = 48;
        } else if ((s & 7) == 0 && D > 0) {
          --D;
        }
      }
      *(float2*)(&hbuf[ps ^ 1][PADI(2 * tid)]) = hv2;
    }
    wg_barrier_lds();  // poll-writes visible; also orders consume-before-
                       // next-produce (carries the skew<2 invariant).
  }
}

__global__ __launch_bounds__(256) void rnn_post(
    const float* __restrict__ hseq, const float* __restrict__ W2,
    const float* __restrict__ b2, float* __restrict__ y) {
  const int t = blockIdx.x;
  const int tid = threadIdx.x;
  __shared__ float hl[H_];
  __shared__ float part[256];
  for (int n = tid; n < H_; n += 256) hl[n] = hseq[t * H_ + n];
  __syncthreads();
  const int o = tid >> 3;
  const int seg = tid & 7;
  float acc = 0.0f;
  if (o < O_) {
    const float4* wp = (const float4*)(W2 + o * H_ + seg * 64);
    const float4* hp = (const float4*)(hl + seg * 64);
#pragma unroll
    for (int j = 0; j < 16; ++j) {
      float4 w4 = wp[j];
      float4 h4 = hp[j];
      acc += w4.x * h4.x + w4.y * h4.y + w4.z * h4.z + w4.w * h4.w;
    }
  }
  part[tid] = acc;
  __syncthreads();
  if (tid < O_) {
    float sum = 0.0f;
#pragma unroll
    for (int j = 0; j < 8; ++j) sum += part[tid * 8 + j];
    y[t * O_ + tid] = sum + b2[tid];
  }
}

extern "C" void kernel_launch(void* const* d_in, const int* in_sizes, int n_in,
                              void* d_out, int out_size, void* d_ws, size_t ws_size,
                              hipStream_t stream) {
  const float* x    = (const float*)d_in[0];
  const float* W_ih = (const float*)d_in[1];
  const float* W_hh = (const float*)d_in[2];
  const float* b_ih = (const float*)d_in[3];
  const float* b_hh = (const float*)d_in[4];
  const float* W2   = (const float*)d_in[5];
  const float* b2   = (const float*)d_in[6];
  float* y = (float*)d_out;

  float* xh = (float*)d_ws;                  // [512*512] xi -> hseq (aliased)
  unsigned* hg = (unsigned*)(xh + S_ * H_);  // [2*512] u32 + [2*512] u64 sc

  rnn_pre<<<dim3(S_, 2), 256, 0, stream>>>(x, W_ih, b_ih, b_hh, xh, hg);
  rnn_seq<<<NC_, 256, 0, stream>>>(W_hh, xh, hg);
  rnn_post<<<S_, 256, 0, stream>>>(xh, W2, b2, y);
}